// Round 6
// baseline (456.947 us; speedup 1.0000x reference)
//
#include <hip/hip_runtime.h>
#include <math.h>

// d_out layout (floats): out1[N*10] | out2[N*20] | h[N*128]
// d_ws layout (fast path, ~39MB):
//   boffs[nb+1] | bcur[nb] | offs[N+1] | ebuf[E] | elist[E]   (ints)
//   aggb[N*128] | wbT[128*256]                                 (bf16/short)
// nb = ceil(N/64) buckets by dst>>6. ebuf holds packed (src<<6)|(dst&63).
// Fallback (ws too small or N too big): atomic-scatter fp32 path.

typedef __attribute__((ext_vector_type(8))) short s16x8;
typedef __attribute__((ext_vector_type(4))) float f32x4;

static __device__ __forceinline__ unsigned short f2b(float f) {
  unsigned u = __builtin_bit_cast(unsigned, f);
  u += 0x7fff + ((u >> 16) & 1);                 // round-to-nearest-even
  return (unsigned short)(u >> 16);
}

// ---------------- bucketed CSR build ----------------

__global__ __launch_bounds__(256) void bucket_hist(
    const int* __restrict__ ei, int* __restrict__ bcnt, int E, int nb)
{
  __shared__ int lcnt[4096];
  for (int i = threadIdx.x; i < nb; i += 256) lcnt[i] = 0;
  __syncthreads();
  int stride = gridDim.x * blockDim.x;
  for (int e = blockIdx.x * blockDim.x + threadIdx.x; e < E; e += stride)
    atomicAdd(&lcnt[ei[(size_t)E + e] >> 6], 1);
  __syncthreads();
  for (int i = threadIdx.x; i < nb; i += 256)
    if (lcnt[i]) atomicAdd(&bcnt[i], lcnt[i]);
}

// single block: exclusive scan of bcur(counts, nb<=4096) -> boffs, reset bcur
__global__ __launch_bounds__(256) void bucket_scan(
    int* __restrict__ bcur, int* __restrict__ boffs, int nb, int E)
{
  __shared__ int s_sum[256];
  const int t = threadIdx.x;
  const int base = t * 16;
  int v[16];
  int s = 0;
#pragma unroll
  for (int k = 0; k < 16; ++k) {
    v[k] = (base + k < nb) ? bcur[base + k] : 0;
    s += v[k];
  }
  s_sum[t] = s;
  __syncthreads();
#pragma unroll
  for (int off = 1; off < 256; off <<= 1) {
    int add = (t >= off) ? s_sum[t - off] : 0;
    __syncthreads();
    s_sum[t] += add;
    __syncthreads();
  }
  int run = s_sum[t] - s;
#pragma unroll
  for (int k = 0; k < 16; ++k) {
    if (base + k < nb) { boffs[base + k] = run; bcur[base + k] = run; }
    run += v[k];
  }
  if (t == 255) boffs[nb] = E;
}

__global__ __launch_bounds__(256) void bucket_scatter(
    const int* __restrict__ ei, int* __restrict__ bcur,
    int* __restrict__ ebuf, int E)
{
  int stride = gridDim.x * blockDim.x;
  for (int e = blockIdx.x * blockDim.x + threadIdx.x; e < E; e += stride) {
    int src = ei[e];
    int dst = ei[(size_t)E + e];
    int pos = atomicAdd(&bcur[dst >> 6], 1);
    ebuf[pos] = (src << 6) | (dst & 63);
  }
}

// one block per bucket: per-node counts/prefix/cursors in LDS -> offs, elist
__global__ __launch_bounds__(256) void csr_finalize(
    const int* __restrict__ boffs, const int* __restrict__ ebuf,
    int* __restrict__ offs, int* __restrict__ elist, int N, int E)
{
  __shared__ int cnt[64];
  __shared__ int curh[64];
  const int b = blockIdx.x;
  const int t = threadIdx.x;
  const int e0 = boffs[b], e1 = boffs[b + 1];

  if (t < 64) cnt[t] = 0;
  __syncthreads();
  for (int j = e0 + t; j < e1; j += 256)
    atomicAdd(&cnt[ebuf[j] & 63], 1);
  __syncthreads();
  if (t < 64) {
    int v = cnt[t];
    int inc = v;
#pragma unroll
    for (int d = 1; d < 64; d <<= 1) {
      int o = __shfl_up(inc, d);
      if (t >= d) inc += o;
    }
    int ex = e0 + inc - v;          // global exclusive offset for this node
    int node = b * 64 + t;
    if (node < N) offs[node] = ex;
    curh[t] = ex;
  }
  if (b == 0 && t == 255) offs[N] = E;
  __syncthreads();
  for (int j = e0 + t; j < e1; j += 256) {
    int v = ebuf[j];
    int pos = atomicAdd(&curh[v & 63], 1);
    elist[pos] = v >> 6;
  }
}

// ---------------- gather (fp32 x, mean, writes bf16 agg) ----------------

__global__ __launch_bounds__(256) void agg_gather(
    const float* __restrict__ x, const int* __restrict__ offs,
    const int* __restrict__ elist, short* __restrict__ aggb, int N)
{
  const int lane = threadIdx.x & 63;
  const int row = blockIdx.x * 4 + (threadIdx.x >> 6);
  if (row >= N) return;
  const int qt = lane >> 4;     // edge slot 0..3
  const int c  = lane & 15;     // float4 column (and c+16)
  const int start = offs[row], end = offs[row + 1];
  float4 a0 = {0.f, 0.f, 0.f, 0.f};
  float4 a1 = {0.f, 0.f, 0.f, 0.f};
  for (int j = start + qt; j < end; j += 4) {
    const float4* xr = (const float4*)x + (size_t)elist[j] * 32;
    float4 v0 = xr[c];
    float4 v1 = xr[c + 16];
    a0.x += v0.x; a0.y += v0.y; a0.z += v0.z; a0.w += v0.w;
    a1.x += v1.x; a1.y += v1.y; a1.z += v1.z; a1.w += v1.w;
  }
#pragma unroll
  for (int m = 16; m <= 32; m <<= 1) {
    a0.x += __shfl_xor(a0.x, m); a0.y += __shfl_xor(a0.y, m);
    a0.z += __shfl_xor(a0.z, m); a0.w += __shfl_xor(a0.w, m);
    a1.x += __shfl_xor(a1.x, m); a1.y += __shfl_xor(a1.y, m);
    a1.z += __shfl_xor(a1.z, m); a1.w += __shfl_xor(a1.w, m);
  }
  if (qt == 0) {
    float rd = 1.0f / fmaxf((float)(end - start), 1.0f);
    ushort4 o0 = { f2b(a0.x * rd), f2b(a0.y * rd), f2b(a0.z * rd), f2b(a0.w * rd) };
    ushort4 o1 = { f2b(a1.x * rd), f2b(a1.y * rd), f2b(a1.z * rd), f2b(a1.w * rd) };
    *(ushort4*)&aggb[(size_t)row * 128 + c * 4]      = o0;
    *(ushort4*)&aggb[(size_t)row * 128 + 64 + c * 4] = o1;
  }
}

// wbT[c][k]: c=0..127 output col, k=0..255 (0..127 from Wl, 128..255 from Wr)
__global__ __launch_bounds__(256) void conv_w_kernel(
    const float* __restrict__ Wl, const float* __restrict__ Wr,
    short* __restrict__ wbT)
{
  int i = blockIdx.x * blockDim.x + threadIdx.x;
  if (i < 128 * 256) {
    int c = i >> 8;
    int k = i & 255;
    float v = (k < 128) ? Wl[(size_t)k * 128 + c] : Wr[(size_t)(k - 128) * 128 + c];
    wbT[i] = (short)f2b(v);
  }
}

// ---------------- MFMA gemm: h = [aggb | bf16(x)] @ wbT^T + bl ----------------
// 128x128 tile, K=256 in 4 chunks of 64. 4 waves (2x2), each wave 64x64 out.

__global__ __launch_bounds__(256, 2) void gemm_mfma(
    const short* __restrict__ aggb, const float* __restrict__ x,
    const short* __restrict__ wbT, const float* __restrict__ bl,
    float* __restrict__ h, int N)
{
  __shared__ short A_s[128][72];   // +8 bf16 pad
  __shared__ short B_s[128][72];   // B_s[col][k]

  const int t = threadIdx.x;
  const int lane = t & 63;
  const int wid = t >> 6;
  const int wr = wid >> 1;
  const int wc = wid & 1;
  const int row0 = blockIdx.x * 128;
  const int l15 = lane & 15;
  const int lhi = lane >> 4;

  f32x4 acc[4][4];
#pragma unroll
  for (int m = 0; m < 4; ++m)
#pragma unroll
    for (int n = 0; n < 4; ++n) acc[m][n] = (f32x4){0.f, 0.f, 0.f, 0.f};

  for (int kc = 0; kc < 4; ++kc) {
    __syncthreads();
    const int kbase = (kc & 1) * 64;
#pragma unroll
    for (int uu = 0; uu < 4; ++uu) {
      int u = t + uu * 256;        // 0..1023
      int r = u >> 3;              // row 0..127
      int s = u & 7;               // 8-short segment 0..7
      s16x8 va = {0, 0, 0, 0, 0, 0, 0, 0};
      int grow = row0 + r;
      if (grow < N) {
        if (kc < 2) {
          va = *(const s16x8*)&aggb[(size_t)grow * 128 + kbase + s * 8];
        } else {
          float4 f0 = ((const float4*)x)[(size_t)grow * 32 + (kc & 1) * 16 + s * 2];
          float4 f1 = ((const float4*)x)[(size_t)grow * 32 + (kc & 1) * 16 + s * 2 + 1];
          va[0] = (short)f2b(f0.x); va[1] = (short)f2b(f0.y);
          va[2] = (short)f2b(f0.z); va[3] = (short)f2b(f0.w);
          va[4] = (short)f2b(f1.x); va[5] = (short)f2b(f1.y);
          va[6] = (short)f2b(f1.z); va[7] = (short)f2b(f1.w);
        }
      }
      *(s16x8*)&A_s[r][s * 8] = va;
      s16x8 vb = *(const s16x8*)&wbT[(size_t)r * 256 + kc * 64 + s * 8];
      *(s16x8*)&B_s[r][s * 8] = vb;
    }
    __syncthreads();

#pragma unroll
    for (int ks = 0; ks < 64; ks += 32) {
      const int klo = ks + lhi * 8;
      s16x8 af[4], bf[4];
#pragma unroll
      for (int m = 0; m < 4; ++m)
        af[m] = *(const s16x8*)&A_s[wr * 64 + m * 16 + l15][klo];
#pragma unroll
      for (int n = 0; n < 4; ++n)
        bf[n] = *(const s16x8*)&B_s[wc * 64 + n * 16 + l15][klo];
#pragma unroll
      for (int m = 0; m < 4; ++m)
#pragma unroll
        for (int n = 0; n < 4; ++n)
          acc[m][n] = __builtin_amdgcn_mfma_f32_16x16x32_bf16(
              af[m], bf[n], acc[m][n], 0, 0, 0);
    }
  }

  // C frag mapping: col=lane&15, row=(lane>>4)*4+reg (m89-verified)
  float bcol[4];
#pragma unroll
  for (int n = 0; n < 4; ++n) bcol[n] = bl[wc * 64 + n * 16 + l15];
#pragma unroll
  for (int m = 0; m < 4; ++m) {
    int grow_base = row0 + wr * 64 + m * 16 + lhi * 4;
#pragma unroll
    for (int r = 0; r < 4; ++r) {
      int grow = grow_base + r;
      if (grow < N) {
#pragma unroll
        for (int n = 0; n < 4; ++n) {
          int col = wc * 64 + n * 16 + l15;
          h[(size_t)grow * 128 + col] = acc[m][n][r] + bcol[n];
        }
      }
    }
  }
}

// ---------------- fallback: atomic scatter + fp32 gemm ----------------

__global__ __launch_bounds__(256) void edge_scatter(
    const float* __restrict__ x, const int* __restrict__ ei,
    float* __restrict__ agg, float* __restrict__ deg, int E)
{
  long long total = (long long)E * 32;
  long long stride = (long long)gridDim.x * blockDim.x;
  for (long long i = (long long)blockIdx.x * blockDim.x + threadIdx.x;
       i < total; i += stride) {
    int e = (int)(i >> 5);
    int c = (int)(i & 31);
    int src = ei[e];
    int dst = ei[(size_t)E + e];
    float4 v = ((const float4*)x)[(size_t)src * 32 + c];
    float* a = agg + (size_t)dst * 128 + c * 4;
    atomicAdd(a + 0, v.x);
    atomicAdd(a + 1, v.y);
    atomicAdd(a + 2, v.z);
    atomicAdd(a + 3, v.w);
    if (c == 0) atomicAdd(deg + dst, 1.0f);
  }
}

#define FMA4(accR, wv, s) { accR[0] += (s) * wv.x; accR[1] += (s) * wv.y; \
                            accR[2] += (s) * wv.z; accR[3] += (s) * wv.w; }

__global__ __launch_bounds__(256, 2) void gemm_h(
    const float* __restrict__ x, const float* __restrict__ Wl,
    const float* __restrict__ bl, const float* __restrict__ Wr,
    const float* __restrict__ degf, float* __restrict__ aggh, int N)
{
  __shared__ float a_s[128][36];
  __shared__ float x_s[128][36];
  __shared__ float wl_s[32][128];
  __shared__ float wr_s[32][128];

  const int t = threadIdx.x;
  const int tx = t & 15;
  const int ty = t >> 4;
  const int row0 = blockIdx.x * 128;

  float acc0[8][4];
  float acc1[8][4];
#pragma unroll
  for (int r = 0; r < 8; ++r)
#pragma unroll
    for (int c = 0; c < 4; ++c) { acc0[r][c] = 0.f; acc1[r][c] = 0.f; }

  for (int kc = 0; kc < 4; ++kc) {
    __syncthreads();
#pragma unroll
    for (int j = 0; j < 4; ++j) {
      int i = t + 256 * j;
      int r = i >> 3;
      int c4 = i & 7;
      int row = row0 + r;
      float4 av = {0.f, 0.f, 0.f, 0.f};
      float4 xv = {0.f, 0.f, 0.f, 0.f};
      if (row < N) {
        float rd = 1.0f / fmaxf(degf[row], 1.0f);
        av = ((const float4*)aggh)[(size_t)row * 32 + kc * 8 + c4];
        av.x *= rd; av.y *= rd; av.z *= rd; av.w *= rd;
        xv = ((const float4*)x)[(size_t)row * 32 + kc * 8 + c4];
      }
      *(float4*)&a_s[r][c4 * 4] = av;
      *(float4*)&x_s[r][c4 * 4] = xv;
    }
#pragma unroll
    for (int j = 0; j < 4; ++j) {
      int i = t + 256 * j;
      int kk = i >> 5;
      int c4 = i & 31;
      ((float4*)wl_s[kk])[c4] = ((const float4*)Wl)[(size_t)(kc * 32 + kk) * 32 + c4];
      ((float4*)wr_s[kk])[c4] = ((const float4*)Wr)[(size_t)(kc * 32 + kk) * 32 + c4];
    }
    __syncthreads();

#pragma unroll
    for (int k4 = 0; k4 < 8; ++k4) {
      float4 wl0[4], wl1[4], wr0[4], wr1[4];
#pragma unroll
      for (int kk = 0; kk < 4; ++kk) {
        int k = k4 * 4 + kk;
        wl0[kk] = *(const float4*)&wl_s[k][tx * 4];
        wl1[kk] = *(const float4*)&wl_s[k][64 + tx * 4];
        wr0[kk] = *(const float4*)&wr_s[k][tx * 4];
        wr1[kk] = *(const float4*)&wr_s[k][64 + tx * 4];
      }
#pragma unroll
      for (int r = 0; r < 8; ++r) {
        int rr = ty + 16 * r;
        float4 a  = *(const float4*)&a_s[rr][k4 * 4];
        float4 xv = *(const float4*)&x_s[rr][k4 * 4];
        FMA4(acc0[r], wl0[0], a.x); FMA4(acc0[r], wl0[1], a.y);
        FMA4(acc0[r], wl0[2], a.z); FMA4(acc0[r], wl0[3], a.w);
        FMA4(acc0[r], wr0[0], xv.x); FMA4(acc0[r], wr0[1], xv.y);
        FMA4(acc0[r], wr0[2], xv.z); FMA4(acc0[r], wr0[3], xv.w);
        FMA4(acc1[r], wl1[0], a.x); FMA4(acc1[r], wl1[1], a.y);
        FMA4(acc1[r], wl1[2], a.z); FMA4(acc1[r], wl1[3], a.w);
        FMA4(acc1[r], wr1[0], xv.x); FMA4(acc1[r], wr1[1], xv.y);
        FMA4(acc1[r], wr1[2], xv.z); FMA4(acc1[r], wr1[3], xv.w);
      }
    }
  }

  float4 b0 = ((const float4*)bl)[tx];
  float4 b1 = ((const float4*)bl)[16 + tx];
#pragma unroll
  for (int r = 0; r < 8; ++r) {
    int row = row0 + ty + 16 * r;
    if (row < N) {
      float4 o0 = { acc0[r][0] + b0.x, acc0[r][1] + b0.y,
                    acc0[r][2] + b0.z, acc0[r][3] + b0.w };
      float4 o1 = { acc1[r][0] + b1.x, acc1[r][1] + b1.y,
                    acc1[r][2] + b1.z, acc1[r][3] + b1.w };
      ((float4*)aggh)[(size_t)row * 32 + tx] = o0;
      ((float4*)aggh)[(size_t)row * 32 + 16 + tx] = o1;
    }
  }
}

// ---------------- heads ----------------

__global__ __launch_bounds__(256) void head_kernel(
    const float* __restrict__ h, const float* __restrict__ W1,
    const float* __restrict__ W2,
    float* __restrict__ out1, float* __restrict__ out2,
    int N, int c1, int c2)
{
  __shared__ float wc_s[30][132];
  __shared__ float wnorm[30];
  const int nc = c1 + c2;

  for (int i = threadIdx.x; i < nc * 128; i += 256) {
    int j = i >> 7, l = i & 127;
    wc_s[j][l] = (j < c1) ? W1[(size_t)l * c1 + j]
                          : W2[(size_t)l * c2 + (j - c1)];
  }
  __syncthreads();
  if (threadIdx.x < nc) {
    float ss = 0.f;
    for (int l = 0; l < 128; ++l) { float v = wc_s[threadIdx.x][l]; ss += v * v; }
    wnorm[threadIdx.x] = 1.0f / fmaxf(sqrtf(ss), 1e-12f);
  }
  __syncthreads();
  for (int i = threadIdx.x; i < nc * 128; i += 256) {
    int j = i >> 7;
    wc_s[j][i & 127] *= wnorm[j];
  }
  __syncthreads();

  int row = blockIdx.x * 256 + threadIdx.x;
  if (row >= N) return;
  const float4* h4 = (const float4*)(h + (size_t)row * 128);
  float acc[30];
#pragma unroll
  for (int j = 0; j < 30; ++j) acc[j] = 0.f;
  float ss = 0.f;
#pragma unroll 4
  for (int kk = 0; kk < 32; ++kk) {
    float4 v = h4[kk];
    ss += v.x * v.x + v.y * v.y + v.z * v.z + v.w * v.w;
#pragma unroll
    for (int j = 0; j < 30; ++j) {
      const float4 w = *(const float4*)&wc_s[j][kk * 4];
      acc[j] += v.x * w.x + v.y * w.y + v.z * w.z + v.w * w.w;
    }
  }
  float scale = 10.0f / fmaxf(sqrtf(ss), 1e-12f);
#pragma unroll
  for (int j = 0; j < 10; ++j) out1[(size_t)row * 10 + j] = scale * acc[j];
#pragma unroll
  for (int j = 0; j < 20; ++j) out2[(size_t)row * 20 + j] = scale * acc[10 + j];
}

// ---------------- launch ----------------

extern "C" void kernel_launch(void* const* d_in, const int* in_sizes, int n_in,
                              void* d_out, int out_size, void* d_ws, size_t ws_size,
                              hipStream_t stream)
{
  const float* x  = (const float*)d_in[0];
  const int*   ei = (const int*)d_in[1];
  const float* Wl = (const float*)d_in[2];
  const float* bl = (const float*)d_in[3];
  const float* Wr = (const float*)d_in[4];
  const float* W1 = (const float*)d_in[5];
  const float* W2 = (const float*)d_in[6];

  const int N  = in_sizes[0] / 128;
  const int E  = in_sizes[1] / 2;
  const int c1 = in_sizes[5] / 128;
  const int c2 = in_sizes[6] / 128;
  const int nb = (N + 63) >> 6;

  float* out1 = (float*)d_out;
  float* out2 = out1 + (size_t)N * c1;
  float* h    = out2 + (size_t)N * c2;

  const size_t need = ((size_t)(2 * nb + 1) + (N + 1) + 2 * (size_t)E) * sizeof(int)
                    + ((size_t)N * 128 + 128 * 256) * sizeof(short);

  if (ws_size >= need && nb <= 4096) {
    int* boffs = (int*)d_ws;                    // nb+1
    int* bcur  = boffs + (nb + 1);              // nb
    int* offs  = bcur + nb;                     // N+1
    int* ebuf  = offs + (N + 1);                // E (packed (src<<6)|dstLow)
    int* elist = ebuf + E;                      // E
    short* aggb = (short*)(elist + E);          // N*128
    short* wbT  = aggb + (size_t)N * 128;       // 128*256

    hipMemsetAsync(bcur, 0, (size_t)nb * sizeof(int), stream);
    bucket_hist<<<256, 256, 0, stream>>>(ei, bcur, E, nb);
    bucket_scan<<<1, 256, 0, stream>>>(bcur, boffs, nb, E);
    bucket_scatter<<<2048, 256, 0, stream>>>(ei, bcur, ebuf, E);
    csr_finalize<<<nb, 256, 0, stream>>>(boffs, ebuf, offs, elist, N, E);
    agg_gather<<<(N + 3) / 4, 256, 0, stream>>>(x, offs, elist, aggb, N);
    conv_w_kernel<<<128, 256, 0, stream>>>(Wl, Wr, wbT);
    gemm_mfma<<<(N + 127) / 128, 256, 0, stream>>>(aggb, x, wbT, bl, h, N);
  } else {
    float* deg = out1;   // borrow out1 region (consumed before head rewrites it)
    hipMemsetAsync(h,   0, (size_t)N * 128 * sizeof(float), stream);
    hipMemsetAsync(deg, 0, (size_t)N * sizeof(float), stream);
    edge_scatter<<<4096, 256, 0, stream>>>(x, ei, h, deg, E);
    gemm_h<<<(N + 127) / 128, 256, 0, stream>>>(x, Wl, bl, Wr, deg, h, N);
  }
  head_kernel<<<(N + 255) / 256, 256, 0, stream>>>(h, W1, W2, out1, out2, N, c1, c2);
}

// Round 7
// 230.315 us; speedup vs baseline: 1.9840x; 1.9840x over previous
//
#include <hip/hip_runtime.h>
#include <math.h>

// d_out layout (floats): out1[N*10] | out2[N*20] | h[N*128]
// d_ws layout (fast path, ~39MB):
//   G[nb*NBLK] | offs[N+1] | ebuf[E] | elist[E]   (ints)
//   aggb[N*128] | wbT[128*256]                    (bf16/short)
// Radix partition: bucket = dst>>8 (256 nodes/bucket, nb<=512), NBLK=128 blocks
// each with private output segments -> no cross-XCD cache-line sharing.
// ebuf holds packed (src<<8)|(dst&255). Fallback: atomic-scatter fp32 path.

typedef __attribute__((ext_vector_type(8))) short s16x8;
typedef __attribute__((ext_vector_type(4))) float f32x4;

#define NBLK 128
#define BLKT 512
#define SH 8
#define BMASK 255

static __device__ __forceinline__ unsigned short f2b(float f) {
  unsigned u = __builtin_bit_cast(unsigned, f);
  u += 0x7fff + ((u >> 16) & 1);                 // round-to-nearest-even
  return (unsigned short)(u >> 16);
}

// ---------------- radix CSR build ----------------

// pass 1: per-block bucket histogram -> G[k*NBLK + b]
__global__ __launch_bounds__(BLKT) void radix_hist(
    const int* __restrict__ ei, int* __restrict__ G, int E, int nb, int CH)
{
  __shared__ int cnt[512];
  const int b = blockIdx.x;
  const int t = threadIdx.x;
  for (int i = t; i < 512; i += BLKT) cnt[i] = 0;
  __syncthreads();
  const int e0 = b * CH, e1 = min(E, e0 + CH);
  for (int e = e0 + t; e < e1; e += BLKT)
    atomicAdd(&cnt[ei[(size_t)E + e] >> SH], 1);
  __syncthreads();
  for (int k = t; k < nb; k += BLKT)
    G[(size_t)k * NBLK + b] = cnt[k];
}

#define SCAN_CHUNK 2048

__global__ __launch_bounds__(256) void scan1_kernel(
    const int* __restrict__ cnt, int* __restrict__ offs,
    int* __restrict__ csum, int n)
{
  __shared__ int s_scan[256];
  const int t = threadIdx.x;
  const int base = blockIdx.x * SCAN_CHUNK + t * 8;
  int v[8];
  int s = 0;
#pragma unroll
  for (int k = 0; k < 8; ++k) {
    v[k] = (base + k < n) ? cnt[base + k] : 0;
    s += v[k];
  }
  s_scan[t] = s;
  __syncthreads();
#pragma unroll
  for (int off = 1; off < 256; off <<= 1) {
    int add = (t >= off) ? s_scan[t - off] : 0;
    __syncthreads();
    s_scan[t] += add;
    __syncthreads();
  }
  int run = s_scan[t] - s;
#pragma unroll
  for (int k = 0; k < 8; ++k) {
    if (base + k < n) offs[base + k] = run;
    run += v[k];
  }
  if (t == 255) csum[blockIdx.x] = s_scan[255];
}

__global__ __launch_bounds__(256) void scan2_kernel(int* __restrict__ csum, int nc)
{
  __shared__ int s_scan[256];
  const int t = threadIdx.x;
  int c = (t < nc) ? csum[t] : 0;
  s_scan[t] = c;
  __syncthreads();
#pragma unroll
  for (int off = 1; off < 256; off <<= 1) {
    int add = (t >= off) ? s_scan[t - off] : 0;
    __syncthreads();
    s_scan[t] += add;
    __syncthreads();
  }
  if (t < nc) csum[t] = s_scan[t] - c;
}

__global__ __launch_bounds__(256) void scan3_add(
    int* __restrict__ G, const int* __restrict__ csum, int n)
{
  int i = blockIdx.x * blockDim.x + threadIdx.x;
  if (i < n) G[i] += csum[i / SCAN_CHUNK];
}

// pass 2: scatter into per-(block,bucket) private segments
__global__ __launch_bounds__(BLKT) void radix_scatter(
    const int* __restrict__ ei, const int* __restrict__ G,
    int* __restrict__ ebuf, int E, int nb, int CH)
{
  __shared__ int cur[512];
  const int b = blockIdx.x;
  const int t = threadIdx.x;
  for (int k = t; k < nb; k += BLKT) cur[k] = G[(size_t)k * NBLK + b];
  __syncthreads();
  const int e0 = b * CH, e1 = min(E, e0 + CH);
  for (int e = e0 + t; e < e1; e += BLKT) {
    int src = ei[e];
    int dst = ei[(size_t)E + e];
    int pos = atomicAdd(&cur[dst >> SH], 1);
    ebuf[pos] = (src << SH) | (dst & BMASK);
  }
}

// one block per bucket (256 nodes): per-node counts/prefix/cursors in LDS
__global__ __launch_bounds__(256) void csr_finalize(
    const int* __restrict__ G, const int* __restrict__ ebuf,
    int* __restrict__ offs, int* __restrict__ elist, int N, int E, int nb)
{
  __shared__ int cnt[256];
  __shared__ int sc[256];
  __shared__ int cur[256];
  const int b = blockIdx.x;
  const int t = threadIdx.x;
  const int e0 = G[(size_t)b * NBLK];
  const int e1 = (b + 1 < nb) ? G[(size_t)(b + 1) * NBLK] : E;

  cnt[t] = 0;
  __syncthreads();
  for (int j = e0 + t; j < e1; j += 256)
    atomicAdd(&cnt[ebuf[j] & BMASK], 1);
  __syncthreads();
  int v = cnt[t];
  sc[t] = v;
  __syncthreads();
#pragma unroll
  for (int off = 1; off < 256; off <<= 1) {
    int add = (t >= off) ? sc[t - off] : 0;
    __syncthreads();
    sc[t] += add;
    __syncthreads();
  }
  int ex = e0 + sc[t] - v;          // global exclusive offset for this node
  int node = (b << SH) + t;
  if (node < N) offs[node] = ex;
  cur[t] = ex;
  if (b == 0 && t == 0) offs[N] = E;
  __syncthreads();
  for (int j = e0 + t; j < e1; j += 256) {
    int w = ebuf[j];
    int pos = atomicAdd(&cur[w & BMASK], 1);
    elist[pos] = w >> SH;
  }
}

// ---------------- gather (fp32 x, mean, writes bf16 agg) ----------------

__global__ __launch_bounds__(256) void agg_gather(
    const float* __restrict__ x, const int* __restrict__ offs,
    const int* __restrict__ elist, short* __restrict__ aggb, int N)
{
  const int lane = threadIdx.x & 63;
  const int row = blockIdx.x * 4 + (threadIdx.x >> 6);
  if (row >= N) return;
  const int qt = lane >> 4;     // edge slot 0..3
  const int c  = lane & 15;     // float4 column (and c+16)
  const int start = offs[row], end = offs[row + 1];
  float4 a0 = {0.f, 0.f, 0.f, 0.f};
  float4 a1 = {0.f, 0.f, 0.f, 0.f};
  for (int j = start + qt; j < end; j += 4) {
    const float4* xr = (const float4*)x + (size_t)elist[j] * 32;
    float4 v0 = xr[c];
    float4 v1 = xr[c + 16];
    a0.x += v0.x; a0.y += v0.y; a0.z += v0.z; a0.w += v0.w;
    a1.x += v1.x; a1.y += v1.y; a1.z += v1.z; a1.w += v1.w;
  }
#pragma unroll
  for (int m = 16; m <= 32; m <<= 1) {
    a0.x += __shfl_xor(a0.x, m); a0.y += __shfl_xor(a0.y, m);
    a0.z += __shfl_xor(a0.z, m); a0.w += __shfl_xor(a0.w, m);
    a1.x += __shfl_xor(a1.x, m); a1.y += __shfl_xor(a1.y, m);
    a1.z += __shfl_xor(a1.z, m); a1.w += __shfl_xor(a1.w, m);
  }
  if (qt == 0) {
    float rd = 1.0f / fmaxf((float)(end - start), 1.0f);
    ushort4 o0 = { f2b(a0.x * rd), f2b(a0.y * rd), f2b(a0.z * rd), f2b(a0.w * rd) };
    ushort4 o1 = { f2b(a1.x * rd), f2b(a1.y * rd), f2b(a1.z * rd), f2b(a1.w * rd) };
    *(ushort4*)&aggb[(size_t)row * 128 + c * 4]      = o0;
    *(ushort4*)&aggb[(size_t)row * 128 + 64 + c * 4] = o1;
  }
}

// wbT[c][k]: c=0..127 output col, k=0..255 (0..127 from Wl, 128..255 from Wr)
__global__ __launch_bounds__(256) void conv_w_kernel(
    const float* __restrict__ Wl, const float* __restrict__ Wr,
    short* __restrict__ wbT)
{
  int i = blockIdx.x * blockDim.x + threadIdx.x;
  if (i < 128 * 256) {
    int c = i >> 8;
    int k = i & 255;
    float v = (k < 128) ? Wl[(size_t)k * 128 + c] : Wr[(size_t)(k - 128) * 128 + c];
    wbT[i] = (short)f2b(v);
  }
}

// ---------------- MFMA gemm: h = [aggb | bf16(x)] @ wbT^T + bl ----------------
// 128x128 tile, K=256 in 4 chunks of 64. 4 waves (2x2), each wave 64x64 out.

__global__ __launch_bounds__(256, 2) void gemm_mfma(
    const short* __restrict__ aggb, const float* __restrict__ x,
    const short* __restrict__ wbT, const float* __restrict__ bl,
    float* __restrict__ h, int N)
{
  __shared__ short A_s[128][72];   // +8 bf16 pad
  __shared__ short B_s[128][72];   // B_s[col][k]

  const int t = threadIdx.x;
  const int lane = t & 63;
  const int wid = t >> 6;
  const int wr = wid >> 1;
  const int wc = wid & 1;
  const int row0 = blockIdx.x * 128;
  const int l15 = lane & 15;
  const int lhi = lane >> 4;

  f32x4 acc[4][4];
#pragma unroll
  for (int m = 0; m < 4; ++m)
#pragma unroll
    for (int n = 0; n < 4; ++n) acc[m][n] = (f32x4){0.f, 0.f, 0.f, 0.f};

  for (int kc = 0; kc < 4; ++kc) {
    __syncthreads();
    const int kbase = (kc & 1) * 64;
#pragma unroll
    for (int uu = 0; uu < 4; ++uu) {
      int u = t + uu * 256;        // 0..1023
      int r = u >> 3;              // row 0..127
      int s = u & 7;               // 8-short segment 0..7
      s16x8 va = {0, 0, 0, 0, 0, 0, 0, 0};
      int grow = row0 + r;
      if (grow < N) {
        if (kc < 2) {
          va = *(const s16x8*)&aggb[(size_t)grow * 128 + kbase + s * 8];
        } else {
          float4 f0 = ((const float4*)x)[(size_t)grow * 32 + (kc & 1) * 16 + s * 2];
          float4 f1 = ((const float4*)x)[(size_t)grow * 32 + (kc & 1) * 16 + s * 2 + 1];
          va[0] = (short)f2b(f0.x); va[1] = (short)f2b(f0.y);
          va[2] = (short)f2b(f0.z); va[3] = (short)f2b(f0.w);
          va[4] = (short)f2b(f1.x); va[5] = (short)f2b(f1.y);
          va[6] = (short)f2b(f1.z); va[7] = (short)f2b(f1.w);
        }
      }
      *(s16x8*)&A_s[r][s * 8] = va;
      s16x8 vb = *(const s16x8*)&wbT[(size_t)r * 256 + kc * 64 + s * 8];
      *(s16x8*)&B_s[r][s * 8] = vb;
    }
    __syncthreads();

#pragma unroll
    for (int ks = 0; ks < 64; ks += 32) {
      const int klo = ks + lhi * 8;
      s16x8 af[4], bf[4];
#pragma unroll
      for (int m = 0; m < 4; ++m)
        af[m] = *(const s16x8*)&A_s[wr * 64 + m * 16 + l15][klo];
#pragma unroll
      for (int n = 0; n < 4; ++n)
        bf[n] = *(const s16x8*)&B_s[wc * 64 + n * 16 + l15][klo];
#pragma unroll
      for (int m = 0; m < 4; ++m)
#pragma unroll
        for (int n = 0; n < 4; ++n)
          acc[m][n] = __builtin_amdgcn_mfma_f32_16x16x32_bf16(
              af[m], bf[n], acc[m][n], 0, 0, 0);
    }
  }

  // C frag mapping: col=lane&15, row=(lane>>4)*4+reg (m89-verified)
  float bcol[4];
#pragma unroll
  for (int n = 0; n < 4; ++n) bcol[n] = bl[wc * 64 + n * 16 + l15];
#pragma unroll
  for (int m = 0; m < 4; ++m) {
    int grow_base = row0 + wr * 64 + m * 16 + lhi * 4;
#pragma unroll
    for (int r = 0; r < 4; ++r) {
      int grow = grow_base + r;
      if (grow < N) {
#pragma unroll
        for (int n = 0; n < 4; ++n) {
          int col = wc * 64 + n * 16 + l15;
          h[(size_t)grow * 128 + col] = acc[m][n][r] + bcol[n];
        }
      }
    }
  }
}

// ---------------- fallback: atomic scatter + fp32 gemm ----------------

__global__ __launch_bounds__(256) void edge_scatter(
    const float* __restrict__ x, const int* __restrict__ ei,
    float* __restrict__ agg, float* __restrict__ deg, int E)
{
  long long total = (long long)E * 32;
  long long stride = (long long)gridDim.x * blockDim.x;
  for (long long i = (long long)blockIdx.x * blockDim.x + threadIdx.x;
       i < total; i += stride) {
    int e = (int)(i >> 5);
    int c = (int)(i & 31);
    int src = ei[e];
    int dst = ei[(size_t)E + e];
    float4 v = ((const float4*)x)[(size_t)src * 32 + c];
    float* a = agg + (size_t)dst * 128 + c * 4;
    atomicAdd(a + 0, v.x);
    atomicAdd(a + 1, v.y);
    atomicAdd(a + 2, v.z);
    atomicAdd(a + 3, v.w);
    if (c == 0) atomicAdd(deg + dst, 1.0f);
  }
}

#define FMA4(accR, wv, s) { accR[0] += (s) * wv.x; accR[1] += (s) * wv.y; \
                            accR[2] += (s) * wv.z; accR[3] += (s) * wv.w; }

__global__ __launch_bounds__(256, 2) void gemm_h(
    const float* __restrict__ x, const float* __restrict__ Wl,
    const float* __restrict__ bl, const float* __restrict__ Wr,
    const float* __restrict__ degf, float* __restrict__ aggh, int N)
{
  __shared__ float a_s[128][36];
  __shared__ float x_s[128][36];
  __shared__ float wl_s[32][128];
  __shared__ float wr_s[32][128];

  const int t = threadIdx.x;
  const int tx = t & 15;
  const int ty = t >> 4;
  const int row0 = blockIdx.x * 128;

  float acc0[8][4];
  float acc1[8][4];
#pragma unroll
  for (int r = 0; r < 8; ++r)
#pragma unroll
    for (int c = 0; c < 4; ++c) { acc0[r][c] = 0.f; acc1[r][c] = 0.f; }

  for (int kc = 0; kc < 4; ++kc) {
    __syncthreads();
#pragma unroll
    for (int j = 0; j < 4; ++j) {
      int i = t + 256 * j;
      int r = i >> 3;
      int c4 = i & 7;
      int row = row0 + r;
      float4 av = {0.f, 0.f, 0.f, 0.f};
      float4 xv = {0.f, 0.f, 0.f, 0.f};
      if (row < N) {
        float rd = 1.0f / fmaxf(degf[row], 1.0f);
        av = ((const float4*)aggh)[(size_t)row * 32 + kc * 8 + c4];
        av.x *= rd; av.y *= rd; av.z *= rd; av.w *= rd;
        xv = ((const float4*)x)[(size_t)row * 32 + kc * 8 + c4];
      }
      *(float4*)&a_s[r][c4 * 4] = av;
      *(float4*)&x_s[r][c4 * 4] = xv;
    }
#pragma unroll
    for (int j = 0; j < 4; ++j) {
      int i = t + 256 * j;
      int kk = i >> 5;
      int c4 = i & 31;
      ((float4*)wl_s[kk])[c4] = ((const float4*)Wl)[(size_t)(kc * 32 + kk) * 32 + c4];
      ((float4*)wr_s[kk])[c4] = ((const float4*)Wr)[(size_t)(kc * 32 + kk) * 32 + c4];
    }
    __syncthreads();

#pragma unroll
    for (int k4 = 0; k4 < 8; ++k4) {
      float4 wl0[4], wl1[4], wr0[4], wr1[4];
#pragma unroll
      for (int kk = 0; kk < 4; ++kk) {
        int k = k4 * 4 + kk;
        wl0[kk] = *(const float4*)&wl_s[k][tx * 4];
        wl1[kk] = *(const float4*)&wl_s[k][64 + tx * 4];
        wr0[kk] = *(const float4*)&wr_s[k][tx * 4];
        wr1[kk] = *(const float4*)&wr_s[k][64 + tx * 4];
      }
#pragma unroll
      for (int r = 0; r < 8; ++r) {
        int rr = ty + 16 * r;
        float4 a  = *(const float4*)&a_s[rr][k4 * 4];
        float4 xv = *(const float4*)&x_s[rr][k4 * 4];
        FMA4(acc0[r], wl0[0], a.x); FMA4(acc0[r], wl0[1], a.y);
        FMA4(acc0[r], wl0[2], a.z); FMA4(acc0[r], wl0[3], a.w);
        FMA4(acc0[r], wr0[0], xv.x); FMA4(acc0[r], wr0[1], xv.y);
        FMA4(acc0[r], wr0[2], xv.z); FMA4(acc0[r], wr0[3], xv.w);
        FMA4(acc1[r], wl1[0], a.x); FMA4(acc1[r], wl1[1], a.y);
        FMA4(acc1[r], wl1[2], a.z); FMA4(acc1[r], wl1[3], a.w);
        FMA4(acc1[r], wr1[0], xv.x); FMA4(acc1[r], wr1[1], xv.y);
        FMA4(acc1[r], wr1[2], xv.z); FMA4(acc1[r], wr1[3], xv.w);
      }
    }
  }

  float4 b0 = ((const float4*)bl)[tx];
  float4 b1 = ((const float4*)bl)[16 + tx];
#pragma unroll
  for (int r = 0; r < 8; ++r) {
    int row = row0 + ty + 16 * r;
    if (row < N) {
      float4 o0 = { acc0[r][0] + b0.x, acc0[r][1] + b0.y,
                    acc0[r][2] + b0.z, acc0[r][3] + b0.w };
      float4 o1 = { acc1[r][0] + b1.x, acc1[r][1] + b1.y,
                    acc1[r][2] + b1.z, acc1[r][3] + b1.w };
      ((float4*)aggh)[(size_t)row * 32 + tx] = o0;
      ((float4*)aggh)[(size_t)row * 32 + 16 + tx] = o1;
    }
  }
}

// ---------------- heads ----------------

__global__ __launch_bounds__(256) void head_kernel(
    const float* __restrict__ h, const float* __restrict__ W1,
    const float* __restrict__ W2,
    float* __restrict__ out1, float* __restrict__ out2,
    int N, int c1, int c2)
{
  __shared__ float wc_s[30][132];
  __shared__ float wnorm[30];
  const int nc = c1 + c2;

  for (int i = threadIdx.x; i < nc * 128; i += 256) {
    int j = i >> 7, l = i & 127;
    wc_s[j][l] = (j < c1) ? W1[(size_t)l * c1 + j]
                          : W2[(size_t)l * c2 + (j - c1)];
  }
  __syncthreads();
  if (threadIdx.x < nc) {
    float ss = 0.f;
    for (int l = 0; l < 128; ++l) { float v = wc_s[threadIdx.x][l]; ss += v * v; }
    wnorm[threadIdx.x] = 1.0f / fmaxf(sqrtf(ss), 1e-12f);
  }
  __syncthreads();
  for (int i = threadIdx.x; i < nc * 128; i += 256) {
    int j = i >> 7;
    wc_s[j][i & 127] *= wnorm[j];
  }
  __syncthreads();

  int row = blockIdx.x * 256 + threadIdx.x;
  if (row >= N) return;
  const float4* h4 = (const float4*)(h + (size_t)row * 128);
  float acc[30];
#pragma unroll
  for (int j = 0; j < 30; ++j) acc[j] = 0.f;
  float ss = 0.f;
#pragma unroll 4
  for (int kk = 0; kk < 32; ++kk) {
    float4 v = h4[kk];
    ss += v.x * v.x + v.y * v.y + v.z * v.z + v.w * v.w;
#pragma unroll
    for (int j = 0; j < 30; ++j) {
      const float4 w = *(const float4*)&wc_s[j][kk * 4];
      acc[j] += v.x * w.x + v.y * w.y + v.z * w.z + v.w * w.w;
    }
  }
  float scale = 10.0f / fmaxf(sqrtf(ss), 1e-12f);
#pragma unroll
  for (int j = 0; j < 10; ++j) out1[(size_t)row * 10 + j] = scale * acc[j];
#pragma unroll
  for (int j = 0; j < 20; ++j) out2[(size_t)row * 20 + j] = scale * acc[10 + j];
}

// ---------------- launch ----------------

extern "C" void kernel_launch(void* const* d_in, const int* in_sizes, int n_in,
                              void* d_out, int out_size, void* d_ws, size_t ws_size,
                              hipStream_t stream)
{
  const float* x  = (const float*)d_in[0];
  const int*   ei = (const int*)d_in[1];
  const float* Wl = (const float*)d_in[2];
  const float* bl = (const float*)d_in[3];
  const float* Wr = (const float*)d_in[4];
  const float* W1 = (const float*)d_in[5];
  const float* W2 = (const float*)d_in[6];

  const int N  = in_sizes[0] / 128;
  const int E  = in_sizes[1] / 2;
  const int c1 = in_sizes[5] / 128;
  const int c2 = in_sizes[6] / 128;
  const int nb = (N + 255) >> SH;          // 256-node buckets
  const int nbk = nb * NBLK;               // hist matrix size
  const int CH = (E + NBLK - 1) / NBLK;    // edges per radix block

  float* out1 = (float*)d_out;
  float* out2 = out1 + (size_t)N * c1;
  float* h    = out2 + (size_t)N * c2;

  const size_t need = ((size_t)nbk + (N + 1) + 2 * (size_t)E + 256) * sizeof(int)
                    + ((size_t)N * 128 + 128 * 256) * sizeof(short);

  if (ws_size >= need && nb <= 512) {
    int* G     = (int*)d_ws;                    // nb*NBLK
    int* csum  = G + nbk;                       // 256 (scan chunk sums)
    int* offs  = csum + 256;                    // N+1
    int* ebuf  = offs + (N + 1);                // E packed (src<<8)|dstLow
    int* elist = ebuf + E;                      // E
    short* aggb = (short*)(elist + E);          // N*128
    short* wbT  = aggb + (size_t)N * 128;       // 128*256
    const int nchunks = (nbk + SCAN_CHUNK - 1) / SCAN_CHUNK;

    radix_hist<<<NBLK, BLKT, 0, stream>>>(ei, G, E, nb, CH);
    scan1_kernel<<<nchunks, 256, 0, stream>>>(G, G, csum, nbk);
    scan2_kernel<<<1, 256, 0, stream>>>(csum, nchunks);
    scan3_add<<<(nbk + 255) / 256, 256, 0, stream>>>(G, csum, nbk);
    radix_scatter<<<NBLK, BLKT, 0, stream>>>(ei, G, ebuf, E, nb, CH);
    csr_finalize<<<nb, 256, 0, stream>>>(G, ebuf, offs, elist, N, E, nb);
    agg_gather<<<(N + 3) / 4, 256, 0, stream>>>(x, offs, elist, aggb, N);
    conv_w_kernel<<<128, 256, 0, stream>>>(Wl, Wr, wbT);
    gemm_mfma<<<(N + 127) / 128, 256, 0, stream>>>(aggb, x, wbT, bl, h, N);
  } else {
    float* deg = out1;   // borrow out1 region (consumed before head rewrites it)
    hipMemsetAsync(h,   0, (size_t)N * 128 * sizeof(float), stream);
    hipMemsetAsync(deg, 0, (size_t)N * sizeof(float), stream);
    edge_scatter<<<4096, 256, 0, stream>>>(x, ei, h, deg, E);
    gemm_h<<<(N + 127) / 128, 256, 0, stream>>>(x, Wl, bl, Wr, deg, h, N);
  }
  head_kernel<<<(N + 255) / 256, 256, 0, stream>>>(h, W1, W2, out1, out2, N, c1, c2);
}

// Round 8
// 199.395 us; speedup vs baseline: 2.2917x; 1.1551x over previous
//
#include <hip/hip_runtime.h>
#include <math.h>

// d_out layout (floats): out1[N*10] | out2[N*20] | h[N*128]
//   The h region temporarily hosts xb (bf16 x, N*128 shorts = first half);
//   xb's lifetime ends at agg_gather, before gemm_mfma overwrites h.
// d_ws layout (fast path, ~39MB):
//   G[nb*NBLK] | csum[256] | offs[N+1] | ebuf[E] | elist[E] | (pad) |
//   aggb[N*128] | wbT[128*256]   (bf16/short)
// Radix partition: bucket = dst>>8 (256 nodes/bucket, nb<=512), NBLK=128 blocks
// each with private output segments -> no cross-XCD cache-line sharing.
// ebuf holds packed (src<<8)|(dst&255). Fallback: atomic-scatter fp32 path.

typedef __attribute__((ext_vector_type(8))) short s16x8;
typedef __attribute__((ext_vector_type(4))) float f32x4;

#define NBLK 128
#define BLKT 512
#define SH 8
#define BMASK 255

static __device__ __forceinline__ unsigned short f2b(float f) {
  unsigned u = __builtin_bit_cast(unsigned, f);
  u += 0x7fff + ((u >> 16) & 1);                 // round-to-nearest-even
  return (unsigned short)(u >> 16);
}
static __device__ __forceinline__ float b2f(unsigned short s) {
  unsigned u = ((unsigned)s) << 16;
  return __builtin_bit_cast(float, u);
}

// ---------------- radix CSR build ----------------

__global__ __launch_bounds__(BLKT) void radix_hist(
    const int* __restrict__ ei, int* __restrict__ G, int E, int nb, int CH)
{
  __shared__ int cnt[512];
  const int b = blockIdx.x;
  const int t = threadIdx.x;
  for (int i = t; i < 512; i += BLKT) cnt[i] = 0;
  __syncthreads();
  const int e0 = b * CH, e1 = min(E, e0 + CH);
  for (int e = e0 + t; e < e1; e += BLKT)
    atomicAdd(&cnt[ei[(size_t)E + e] >> SH], 1);
  __syncthreads();
  for (int k = t; k < nb; k += BLKT)
    G[(size_t)k * NBLK + b] = cnt[k];
}

#define SCAN_CHUNK 2048

__global__ __launch_bounds__(256) void scan1_kernel(
    const int* __restrict__ cnt, int* __restrict__ offs,
    int* __restrict__ csum, int n)
{
  __shared__ int s_scan[256];
  const int t = threadIdx.x;
  const int base = blockIdx.x * SCAN_CHUNK + t * 8;
  int v[8];
  int s = 0;
#pragma unroll
  for (int k = 0; k < 8; ++k) {
    v[k] = (base + k < n) ? cnt[base + k] : 0;
    s += v[k];
  }
  s_scan[t] = s;
  __syncthreads();
#pragma unroll
  for (int off = 1; off < 256; off <<= 1) {
    int add = (t >= off) ? s_scan[t - off] : 0;
    __syncthreads();
    s_scan[t] += add;
    __syncthreads();
  }
  int run = s_scan[t] - s;
#pragma unroll
  for (int k = 0; k < 8; ++k) {
    if (base + k < n) offs[base + k] = run;
    run += v[k];
  }
  if (t == 255) csum[blockIdx.x] = s_scan[255];
}

__global__ __launch_bounds__(256) void scan2_kernel(int* __restrict__ csum, int nc)
{
  __shared__ int s_scan[256];
  const int t = threadIdx.x;
  int c = (t < nc) ? csum[t] : 0;
  s_scan[t] = c;
  __syncthreads();
#pragma unroll
  for (int off = 1; off < 256; off <<= 1) {
    int add = (t >= off) ? s_scan[t - off] : 0;
    __syncthreads();
    s_scan[t] += add;
    __syncthreads();
  }
  if (t < nc) csum[t] = s_scan[t] - c;
}

__global__ __launch_bounds__(256) void scan3_add(
    int* __restrict__ G, const int* __restrict__ csum, int n)
{
  int i = blockIdx.x * blockDim.x + threadIdx.x;
  if (i < n) G[i] += csum[i / SCAN_CHUNK];
}

__global__ __launch_bounds__(BLKT) void radix_scatter(
    const int* __restrict__ ei, const int* __restrict__ G,
    int* __restrict__ ebuf, int E, int nb, int CH)
{
  __shared__ int cur[512];
  const int b = blockIdx.x;
  const int t = threadIdx.x;
  for (int k = t; k < nb; k += BLKT) cur[k] = G[(size_t)k * NBLK + b];
  __syncthreads();
  const int e0 = b * CH, e1 = min(E, e0 + CH);
  for (int e = e0 + t; e < e1; e += BLKT) {
    int src = ei[e];
    int dst = ei[(size_t)E + e];
    int pos = atomicAdd(&cur[dst >> SH], 1);
    ebuf[pos] = (src << SH) | (dst & BMASK);
  }
}

__global__ __launch_bounds__(256) void csr_finalize(
    const int* __restrict__ G, const int* __restrict__ ebuf,
    int* __restrict__ offs, int* __restrict__ elist, int N, int E, int nb)
{
  __shared__ int cnt[256];
  __shared__ int sc[256];
  __shared__ int cur[256];
  const int b = blockIdx.x;
  const int t = threadIdx.x;
  const int e0 = G[(size_t)b * NBLK];
  const int e1 = (b + 1 < nb) ? G[(size_t)(b + 1) * NBLK] : E;

  cnt[t] = 0;
  __syncthreads();
  for (int j = e0 + t; j < e1; j += 256)
    atomicAdd(&cnt[ebuf[j] & BMASK], 1);
  __syncthreads();
  int v = cnt[t];
  sc[t] = v;
  __syncthreads();
#pragma unroll
  for (int off = 1; off < 256; off <<= 1) {
    int add = (t >= off) ? sc[t - off] : 0;
    __syncthreads();
    sc[t] += add;
    __syncthreads();
  }
  int ex = e0 + sc[t] - v;
  int node = (b << SH) + t;
  if (node < N) offs[node] = ex;
  cur[t] = ex;
  if (b == 0 && t == 0) offs[N] = E;
  __syncthreads();
  for (int j = e0 + t; j < e1; j += 256) {
    int w = ebuf[j];
    int pos = atomicAdd(&cur[w & BMASK], 1);
    elist[pos] = w >> SH;
  }
}

// ---------------- bf16 conversion of x (into d_out h region) ----------------

__global__ __launch_bounds__(256) void conv_x_kernel(
    const float* __restrict__ x, short* __restrict__ xb, int n8)
{
  int stride = gridDim.x * blockDim.x;
  for (int i = blockIdx.x * blockDim.x + threadIdx.x; i < n8; i += stride) {
    float4 v0 = ((const float4*)x)[(size_t)i * 2];
    float4 v1 = ((const float4*)x)[(size_t)i * 2 + 1];
    s16x8 o;
    o[0] = (short)f2b(v0.x); o[1] = (short)f2b(v0.y);
    o[2] = (short)f2b(v0.z); o[3] = (short)f2b(v0.w);
    o[4] = (short)f2b(v1.x); o[5] = (short)f2b(v1.y);
    o[6] = (short)f2b(v1.z); o[7] = (short)f2b(v1.w);
    ((s16x8*)xb)[i] = o;
  }
}

// ---------------- gather (bf16 xb, fp32 accum, mean, writes bf16 agg) -------

__global__ __launch_bounds__(256) void agg_gather_b(
    const short* __restrict__ xb, const int* __restrict__ offs,
    const int* __restrict__ elist, short* __restrict__ aggb, int N)
{
  const int lane = threadIdx.x & 63;
  const int row = blockIdx.x * 4 + (threadIdx.x >> 6);
  if (row >= N) return;
  const int qt = lane >> 4;     // edge slot 0..3
  const int c  = lane & 15;     // 8-bf16 segment
  const int start = offs[row], end = offs[row + 1];
  float a[8] = {0.f, 0.f, 0.f, 0.f, 0.f, 0.f, 0.f, 0.f};
  for (int j = start + qt; j < end; j += 4) {
    const s16x8 v = *(const s16x8*)&xb[(size_t)elist[j] * 128 + c * 8];
#pragma unroll
    for (int k = 0; k < 8; ++k) a[k] += b2f((unsigned short)v[k]);
  }
#pragma unroll
  for (int k = 0; k < 8; ++k) {
    a[k] += __shfl_xor(a[k], 16);
    a[k] += __shfl_xor(a[k], 32);
  }
  if (qt == 0) {
    float rd = 1.0f / fmaxf((float)(end - start), 1.0f);
    s16x8 o;
#pragma unroll
    for (int k = 0; k < 8; ++k) o[k] = (short)f2b(a[k] * rd);
    *(s16x8*)&aggb[(size_t)row * 128 + c * 8] = o;
  }
}

// wbT[c][k]: c=0..127 output col, k=0..255 (0..127 from Wl, 128..255 from Wr)
__global__ __launch_bounds__(256) void conv_w_kernel(
    const float* __restrict__ Wl, const float* __restrict__ Wr,
    short* __restrict__ wbT)
{
  int i = blockIdx.x * blockDim.x + threadIdx.x;
  if (i < 128 * 256) {
    int c = i >> 8;
    int k = i & 255;
    float v = (k < 128) ? Wl[(size_t)k * 128 + c] : Wr[(size_t)(k - 128) * 128 + c];
    wbT[i] = (short)f2b(v);
  }
}

// ---------------- MFMA gemm: h = [aggb | bf16(x)] @ wbT^T + bl ----------------

__global__ __launch_bounds__(256, 2) void gemm_mfma(
    const short* __restrict__ aggb, const float* __restrict__ x,
    const short* __restrict__ wbT, const float* __restrict__ bl,
    float* __restrict__ h, int N)
{
  __shared__ short A_s[128][72];   // +8 bf16 pad
  __shared__ short B_s[128][72];   // B_s[col][k]

  const int t = threadIdx.x;
  const int lane = t & 63;
  const int wid = t >> 6;
  const int wr = wid >> 1;
  const int wc = wid & 1;
  const int row0 = blockIdx.x * 128;
  const int l15 = lane & 15;
  const int lhi = lane >> 4;

  f32x4 acc[4][4];
#pragma unroll
  for (int m = 0; m < 4; ++m)
#pragma unroll
    for (int n = 0; n < 4; ++n) acc[m][n] = (f32x4){0.f, 0.f, 0.f, 0.f};

  for (int kc = 0; kc < 4; ++kc) {
    __syncthreads();
    const int kbase = (kc & 1) * 64;
#pragma unroll
    for (int uu = 0; uu < 4; ++uu) {
      int u = t + uu * 256;        // 0..1023
      int r = u >> 3;              // row 0..127
      int s = u & 7;               // 8-short segment 0..7
      s16x8 va = {0, 0, 0, 0, 0, 0, 0, 0};
      int grow = row0 + r;
      if (grow < N) {
        if (kc < 2) {
          va = *(const s16x8*)&aggb[(size_t)grow * 128 + kbase + s * 8];
        } else {
          float4 f0 = ((const float4*)x)[(size_t)grow * 32 + (kc & 1) * 16 + s * 2];
          float4 f1 = ((const float4*)x)[(size_t)grow * 32 + (kc & 1) * 16 + s * 2 + 1];
          va[0] = (short)f2b(f0.x); va[1] = (short)f2b(f0.y);
          va[2] = (short)f2b(f0.z); va[3] = (short)f2b(f0.w);
          va[4] = (short)f2b(f1.x); va[5] = (short)f2b(f1.y);
          va[6] = (short)f2b(f1.z); va[7] = (short)f2b(f1.w);
        }
      }
      *(s16x8*)&A_s[r][s * 8] = va;
      s16x8 vb = *(const s16x8*)&wbT[(size_t)r * 256 + kc * 64 + s * 8];
      *(s16x8*)&B_s[r][s * 8] = vb;
    }
    __syncthreads();

#pragma unroll
    for (int ks = 0; ks < 64; ks += 32) {
      const int klo = ks + lhi * 8;
      s16x8 af[4], bf[4];
#pragma unroll
      for (int m = 0; m < 4; ++m)
        af[m] = *(const s16x8*)&A_s[wr * 64 + m * 16 + l15][klo];
#pragma unroll
      for (int n = 0; n < 4; ++n)
        bf[n] = *(const s16x8*)&B_s[wc * 64 + n * 16 + l15][klo];
#pragma unroll
      for (int m = 0; m < 4; ++m)
#pragma unroll
        for (int n = 0; n < 4; ++n)
          acc[m][n] = __builtin_amdgcn_mfma_f32_16x16x32_bf16(
              af[m], bf[n], acc[m][n], 0, 0, 0);
    }
  }

  // C frag mapping: col=lane&15, row=(lane>>4)*4+reg (m89-verified)
  float bcol[4];
#pragma unroll
  for (int n = 0; n < 4; ++n) bcol[n] = bl[wc * 64 + n * 16 + l15];
#pragma unroll
  for (int m = 0; m < 4; ++m) {
    int grow_base = row0 + wr * 64 + m * 16 + lhi * 4;
#pragma unroll
    for (int r = 0; r < 4; ++r) {
      int grow = grow_base + r;
      if (grow < N) {
#pragma unroll
        for (int n = 0; n < 4; ++n) {
          int col = wc * 64 + n * 16 + l15;
          h[(size_t)grow * 128 + col] = acc[m][n][r] + bcol[n];
        }
      }
    }
  }
}

// ---------------- fallback: atomic scatter + fp32 gemm ----------------

__global__ __launch_bounds__(256) void edge_scatter(
    const float* __restrict__ x, const int* __restrict__ ei,
    float* __restrict__ agg, float* __restrict__ deg, int E)
{
  long long total = (long long)E * 32;
  long long stride = (long long)gridDim.x * blockDim.x;
  for (long long i = (long long)blockIdx.x * blockDim.x + threadIdx.x;
       i < total; i += stride) {
    int e = (int)(i >> 5);
    int c = (int)(i & 31);
    int src = ei[e];
    int dst = ei[(size_t)E + e];
    float4 v = ((const float4*)x)[(size_t)src * 32 + c];
    float* a = agg + (size_t)dst * 128 + c * 4;
    atomicAdd(a + 0, v.x);
    atomicAdd(a + 1, v.y);
    atomicAdd(a + 2, v.z);
    atomicAdd(a + 3, v.w);
    if (c == 0) atomicAdd(deg + dst, 1.0f);
  }
}

#define FMA4(accR, wv, s) { accR[0] += (s) * wv.x; accR[1] += (s) * wv.y; \
                            accR[2] += (s) * wv.z; accR[3] += (s) * wv.w; }

__global__ __launch_bounds__(256, 2) void gemm_h(
    const float* __restrict__ x, const float* __restrict__ Wl,
    const float* __restrict__ bl, const float* __restrict__ Wr,
    const float* __restrict__ degf, float* __restrict__ aggh, int N)
{
  __shared__ float a_s[128][36];
  __shared__ float x_s[128][36];
  __shared__ float wl_s[32][128];
  __shared__ float wr_s[32][128];

  const int t = threadIdx.x;
  const int tx = t & 15;
  const int ty = t >> 4;
  const int row0 = blockIdx.x * 128;

  float acc0[8][4];
  float acc1[8][4];
#pragma unroll
  for (int r = 0; r < 8; ++r)
#pragma unroll
    for (int c = 0; c < 4; ++c) { acc0[r][c] = 0.f; acc1[r][c] = 0.f; }

  for (int kc = 0; kc < 4; ++kc) {
    __syncthreads();
#pragma unroll
    for (int j = 0; j < 4; ++j) {
      int i = t + 256 * j;
      int r = i >> 3;
      int c4 = i & 7;
      int row = row0 + r;
      float4 av = {0.f, 0.f, 0.f, 0.f};
      float4 xv = {0.f, 0.f, 0.f, 0.f};
      if (row < N) {
        float rd = 1.0f / fmaxf(degf[row], 1.0f);
        av = ((const float4*)aggh)[(size_t)row * 32 + kc * 8 + c4];
        av.x *= rd; av.y *= rd; av.z *= rd; av.w *= rd;
        xv = ((const float4*)x)[(size_t)row * 32 + kc * 8 + c4];
      }
      *(float4*)&a_s[r][c4 * 4] = av;
      *(float4*)&x_s[r][c4 * 4] = xv;
    }
#pragma unroll
    for (int j = 0; j < 4; ++j) {
      int i = t + 256 * j;
      int kk = i >> 5;
      int c4 = i & 31;
      ((float4*)wl_s[kk])[c4] = ((const float4*)Wl)[(size_t)(kc * 32 + kk) * 32 + c4];
      ((float4*)wr_s[kk])[c4] = ((const float4*)Wr)[(size_t)(kc * 32 + kk) * 32 + c4];
    }
    __syncthreads();

#pragma unroll
    for (int k4 = 0; k4 < 8; ++k4) {
      float4 wl0[4], wl1[4], wr0[4], wr1[4];
#pragma unroll
      for (int kk = 0; kk < 4; ++kk) {
        int k = k4 * 4 + kk;
        wl0[kk] = *(const float4*)&wl_s[k][tx * 4];
        wl1[kk] = *(const float4*)&wl_s[k][64 + tx * 4];
        wr0[kk] = *(const float4*)&wr_s[k][tx * 4];
        wr1[kk] = *(const float4*)&wr_s[k][64 + tx * 4];
      }
#pragma unroll
      for (int r = 0; r < 8; ++r) {
        int rr = ty + 16 * r;
        float4 a  = *(const float4*)&a_s[rr][k4 * 4];
        float4 xv = *(const float4*)&x_s[rr][k4 * 4];
        FMA4(acc0[r], wl0[0], a.x); FMA4(acc0[r], wl0[1], a.y);
        FMA4(acc0[r], wl0[2], a.z); FMA4(acc0[r], wl0[3], a.w);
        FMA4(acc0[r], wr0[0], xv.x); FMA4(acc0[r], wr0[1], xv.y);
        FMA4(acc0[r], wr0[2], xv.z); FMA4(acc0[r], wr0[3], xv.w);
        FMA4(acc1[r], wl1[0], a.x); FMA4(acc1[r], wl1[1], a.y);
        FMA4(acc1[r], wl1[2], a.z); FMA4(acc1[r], wl1[3], a.w);
        FMA4(acc1[r], wr1[0], xv.x); FMA4(acc1[r], wr1[1], xv.y);
        FMA4(acc1[r], wr1[2], xv.z); FMA4(acc1[r], wr1[3], xv.w);
      }
    }
  }

  float4 b0 = ((const float4*)bl)[tx];
  float4 b1 = ((const float4*)bl)[16 + tx];
#pragma unroll
  for (int r = 0; r < 8; ++r) {
    int row = row0 + ty + 16 * r;
    if (row < N) {
      float4 o0 = { acc0[r][0] + b0.x, acc0[r][1] + b0.y,
                    acc0[r][2] + b0.z, acc0[r][3] + b0.w };
      float4 o1 = { acc1[r][0] + b1.x, acc1[r][1] + b1.y,
                    acc1[r][2] + b1.z, acc1[r][3] + b1.w };
      ((float4*)aggh)[(size_t)row * 32 + tx] = o0;
      ((float4*)aggh)[(size_t)row * 32 + 16 + tx] = o1;
    }
  }
}

// ---------------- heads ----------------

__global__ __launch_bounds__(256) void head_kernel(
    const float* __restrict__ h, const float* __restrict__ W1,
    const float* __restrict__ W2,
    float* __restrict__ out1, float* __restrict__ out2,
    int N, int c1, int c2)
{
  __shared__ float wc_s[30][132];
  __shared__ float wnorm[30];
  const int nc = c1 + c2;

  for (int i = threadIdx.x; i < nc * 128; i += 256) {
    int j = i >> 7, l = i & 127;
    wc_s[j][l] = (j < c1) ? W1[(size_t)l * c1 + j]
                          : W2[(size_t)l * c2 + (j - c1)];
  }
  __syncthreads();
  if (threadIdx.x < nc) {
    float ss = 0.f;
    for (int l = 0; l < 128; ++l) { float v = wc_s[threadIdx.x][l]; ss += v * v; }
    wnorm[threadIdx.x] = 1.0f / fmaxf(sqrtf(ss), 1e-12f);
  }
  __syncthreads();
  for (int i = threadIdx.x; i < nc * 128; i += 256) {
    int j = i >> 7;
    wc_s[j][i & 127] *= wnorm[j];
  }
  __syncthreads();

  int row = blockIdx.x * 256 + threadIdx.x;
  if (row >= N) return;
  const float4* h4 = (const float4*)(h + (size_t)row * 128);
  float acc[30];
#pragma unroll
  for (int j = 0; j < 30; ++j) acc[j] = 0.f;
  float ss = 0.f;
#pragma unroll 4
  for (int kk = 0; kk < 32; ++kk) {
    float4 v = h4[kk];
    ss += v.x * v.x + v.y * v.y + v.z * v.z + v.w * v.w;
#pragma unroll
    for (int j = 0; j < 30; ++j) {
      const float4 w = *(const float4*)&wc_s[j][kk * 4];
      acc[j] += v.x * w.x + v.y * w.y + v.z * w.z + v.w * w.w;
    }
  }
  float scale = 10.0f / fmaxf(sqrtf(ss), 1e-12f);
#pragma unroll
  for (int j = 0; j < 10; ++j) out1[(size_t)row * 10 + j] = scale * acc[j];
#pragma unroll
  for (int j = 0; j < 20; ++j) out2[(size_t)row * 20 + j] = scale * acc[10 + j];
}

// ---------------- launch ----------------

extern "C" void kernel_launch(void* const* d_in, const int* in_sizes, int n_in,
                              void* d_out, int out_size, void* d_ws, size_t ws_size,
                              hipStream_t stream)
{
  const float* x  = (const float*)d_in[0];
  const int*   ei = (const int*)d_in[1];
  const float* Wl = (const float*)d_in[2];
  const float* bl = (const float*)d_in[3];
  const float* Wr = (const float*)d_in[4];
  const float* W1 = (const float*)d_in[5];
  const float* W2 = (const float*)d_in[6];

  const int N  = in_sizes[0] / 128;
  const int E  = in_sizes[1] / 2;
  const int c1 = in_sizes[5] / 128;
  const int c2 = in_sizes[6] / 128;
  const int nb = (N + 255) >> SH;          // 256-node buckets
  const int nbk = nb * NBLK;               // hist matrix size
  const int CH = (E + NBLK - 1) / NBLK;    // edges per radix block

  float* out1 = (float*)d_out;
  float* out2 = out1 + (size_t)N * c1;
  float* h    = out2 + (size_t)N * c2;

  // ints, rounded up to multiple of 4 so the short region is 16B-aligned
  size_t ints = (size_t)nbk + 256 + (N + 1) + 2 * (size_t)E;
  ints = (ints + 3) & ~(size_t)3;
  const size_t need = ints * sizeof(int)
                    + ((size_t)N * 128 + 128 * 256) * sizeof(short);

  if (ws_size >= need && nb <= 512) {
    int* G     = (int*)d_ws;                    // nb*NBLK
    int* csum  = G + nbk;                       // 256 (scan chunk sums)
    int* offs  = csum + 256;                    // N+1
    int* ebuf  = offs + (N + 1);                // E packed (src<<8)|dstLow
    int* elist = ebuf + E;                      // E
    short* aggb = (short*)((int*)d_ws + ints);  // N*128 (16B-aligned)
    short* wbT  = aggb + (size_t)N * 128;       // 128*256
    short* xb   = (short*)h;                    // borrow h region for bf16 x
    const int nchunks = (nbk + SCAN_CHUNK - 1) / SCAN_CHUNK;

    conv_x_kernel<<<2048, 256, 0, stream>>>(x, xb, N * 16);
    radix_hist<<<NBLK, BLKT, 0, stream>>>(ei, G, E, nb, CH);
    scan1_kernel<<<nchunks, 256, 0, stream>>>(G, G, csum, nbk);
    scan2_kernel<<<1, 256, 0, stream>>>(csum, nchunks);
    scan3_add<<<(nbk + 255) / 256, 256, 0, stream>>>(G, csum, nbk);
    radix_scatter<<<NBLK, BLKT, 0, stream>>>(ei, G, ebuf, E, nb, CH);
    csr_finalize<<<nb, 256, 0, stream>>>(G, ebuf, offs, elist, N, E, nb);
    agg_gather_b<<<(N + 3) / 4, 256, 0, stream>>>(xb, offs, elist, aggb, N);
    conv_w_kernel<<<128, 256, 0, stream>>>(Wl, Wr, wbT);
    gemm_mfma<<<(N + 127) / 128, 256, 0, stream>>>(aggb, x, wbT, bl, h, N);
  } else {
    float* deg = out1;   // borrow out1 region (consumed before head rewrites it)
    hipMemsetAsync(h,   0, (size_t)N * 128 * sizeof(float), stream);
    hipMemsetAsync(deg, 0, (size_t)N * sizeof(float), stream);
    edge_scatter<<<4096, 256, 0, stream>>>(x, ei, h, deg, E);
    gemm_h<<<(N + 127) / 128, 256, 0, stream>>>(x, Wl, bl, Wr, deg, h, N);
  }
  head_kernel<<<(N + 255) / 256, 256, 0, stream>>>(h, W1, W2, out1, out2, N, c1, c2);
}